// Round 8
// baseline (481.413 us; speedup 1.0000x reference)
//
#include <hip/hip_runtime.h>

#define NEG_SLOPE 0.01f

constexpr int N_NODES_C = 50000;
constexpr int N_EDGES_C = 800000;
constexpr int M_PAD = 50048;  // 391 * 128

typedef short bf16x8 __attribute__((ext_vector_type(8)));
typedef float f32x4 __attribute__((ext_vector_type(4)));

__device__ inline unsigned short f2bf(float f) {
  unsigned int u = __float_as_uint(f);
  u += 0x7FFF + ((u >> 16) & 1);  // round-to-nearest-even
  return (unsigned short)(u >> 16);
}
__device__ inline float bf2f(unsigned int h16) {
  return __uint_as_float(h16 << 16);
}

// ---------------- fused preprocessing ----------------
constexpr int NB_CONVX = (M_PAD * 32) / 256;          // 6256
constexpr int NB_W1 = (256 * 256) / 256;              // 256
constexpr int NB_W2 = (256 * 128) / 256;              // 128
constexpr int NB_HIST = N_EDGES_C / 256;              // 3125
constexpr int NB_PRE = NB_CONVX + NB_W1 + NB_W2 + NB_HIST;

__global__ __launch_bounds__(256) void pre_kernel(
    const float* __restrict__ x, const float* __restrict__ w1,
    const float* __restrict__ w2, const int* __restrict__ dst,
    unsigned short* __restrict__ xb, unsigned short* __restrict__ w1T,
    unsigned short* __restrict__ w2T, int* __restrict__ counts) {
  const int bx = blockIdx.x;
  const int tid = threadIdx.x;
  if (bx < NB_CONVX) {
    int idx = bx * 256 + tid;
    int row = idx >> 5;
    int c8 = (idx & 31) << 3;
    uint4 v;
    if (row < N_NODES_C) {
      const float4* p = (const float4*)(x + (size_t)row * 256 + c8);
      float4 a = p[0], b = p[1];
      v.x = f2bf(a.x) | ((unsigned)f2bf(a.y) << 16);
      v.y = f2bf(a.z) | ((unsigned)f2bf(a.w) << 16);
      v.z = f2bf(b.x) | ((unsigned)f2bf(b.y) << 16);
      v.w = f2bf(b.z) | ((unsigned)f2bf(b.w) << 16);
    } else {
      v = make_uint4(0, 0, 0, 0);
    }
    *(uint4*)(xb + (size_t)row * 256 + c8) = v;
  } else if (bx < NB_CONVX + NB_W1) {
    int idx = (bx - NB_CONVX) * 256 + tid;  // over [N=256][K=256]
    int n = idx >> 8, k = idx & 255;
    w1T[idx] = f2bf(w1[(size_t)k * 256 + n]);
  } else if (bx < NB_CONVX + NB_W1 + NB_W2) {
    int idx = (bx - NB_CONVX - NB_W1) * 256 + tid;  // over [N=128][K=256]
    int n = idx >> 8, k = idx & 255;
    w2T[idx] = f2bf(w2[(size_t)k * 128 + n]);
  } else {
    int e = (bx - NB_CONVX - NB_W1 - NB_W2) * 256 + tid;
    atomicAdd(&counts[dst[e]], 1);
  }
}

// ---------------- hierarchical scan ----------------
constexpr int N_SCAN_BLKS = (N_NODES_C + 255) / 256;  // 196

__global__ __launch_bounds__(256) void scan_phase_a(const int* __restrict__ counts,
                                                    int* __restrict__ partial,
                                                    int* __restrict__ blk_sums) {
  __shared__ int s[256];
  const int t = threadIdx.x;
  const int i = blockIdx.x * 256 + t;
  const int v = (i < N_NODES_C) ? counts[i] : 0;
  s[t] = v;
  __syncthreads();
  for (int off = 1; off < 256; off <<= 1) {
    int u = (t >= off) ? s[t - off] : 0;
    __syncthreads();
    s[t] += u;
    __syncthreads();
  }
  if (i < N_NODES_C) partial[i] = s[t] - v;
  if (t == 255) blk_sums[blockIdx.x] = s[255];
}

__global__ __launch_bounds__(256) void scan_phase_b(const int* __restrict__ blk_sums,
                                                    int* __restrict__ blk_off) {
  __shared__ int s[256];
  const int t = threadIdx.x;
  const int v = (t < N_SCAN_BLKS) ? blk_sums[t] : 0;
  s[t] = v;
  __syncthreads();
  for (int off = 1; off < 256; off <<= 1) {
    int u = (t >= off) ? s[t - off] : 0;
    __syncthreads();
    s[t] += u;
    __syncthreads();
  }
  if (t < N_SCAN_BLKS) blk_off[t] = s[t] - v;
}

__global__ __launch_bounds__(256) void scan_phase_c(const int* __restrict__ partial,
                                                    const int* __restrict__ blk_off,
                                                    int* __restrict__ row_ptr,
                                                    int* __restrict__ cursor) {
  const int i = blockIdx.x * 256 + threadIdx.x;
  if (i < N_NODES_C) {
    const int r = partial[i] + blk_off[blockIdx.x];
    row_ptr[i] = r;
    cursor[i] = r;
  }
  if (i == 0) row_ptr[N_NODES_C] = N_EDGES_C;
}

__global__ __launch_bounds__(256) void fill_kernel(const int* __restrict__ src,
                                                   const int* __restrict__ dst,
                                                   const float* __restrict__ ew,
                                                   int* __restrict__ cursor,
                                                   uint2* __restrict__ s_meta) {
  int e = blockIdx.x * 256 + threadIdx.x;
  if (e < N_EDGES_C) {
    int p = atomicAdd(&cursor[dst[e]], 1);
    uint2 m;
    m.x = (unsigned)src[e];
    m.y = __float_as_uint(ew[e]);
    s_meta[p] = m;
  }
}

// ---------------- bf16 MFMA GEMM with SLICED output ----------------

#define GLOAD_LDS16(g, l)                                              \
  __builtin_amdgcn_global_load_lds(                                    \
      (__attribute__((address_space(1))) void*)(g),                    \
      (__attribute__((address_space(3))) void*)(l), 16, 0, 0)

__global__ __launch_bounds__(256) void gemm_bf16_kernel(
    const unsigned short* __restrict__ A,   // [M_PAD][256] bf16
    const unsigned short* __restrict__ BT,  // [N][256] bf16
    unsigned short* __restrict__ C,         // [N/32][M_PAD][32] bf16 sliced
    int N) {
  constexpr int K = 256;
  __shared__ short Asm[128 * 32];
  __shared__ short Bsm[128 * 32];
  const int tid = threadIdx.x;
  const int lane = tid & 63, wave = tid >> 6;
  const int wm = wave & 1, wn = wave >> 1;
  const int row0 = blockIdx.y * 128, col0 = blockIdx.x * 128;

  const int ch0 = wave * 2, ch1 = wave * 2 + 1;
  const int o0 = ch0 * 512 + lane * 8;
  const int o1 = ch1 * 512 + lane * 8;
  const int r0 = o0 >> 5, c0 = o0 & 31;
  const int r1 = o1 >> 5, c1 = o1 & 31;

  f32x4 acc[4][4] = {};

  for (int k0 = 0; k0 < K; k0 += 32) {
    GLOAD_LDS16(A + (size_t)(row0 + r0) * K + k0 + c0, &Asm[ch0 * 512]);
    GLOAD_LDS16(A + (size_t)(row0 + r1) * K + k0 + c1, &Asm[ch1 * 512]);
    GLOAD_LDS16(BT + (size_t)(col0 + r0) * K + k0 + c0, &Bsm[ch0 * 512]);
    GLOAD_LDS16(BT + (size_t)(col0 + r1) * K + k0 + c1, &Bsm[ch1 * 512]);
    __builtin_amdgcn_s_waitcnt(0);
    __syncthreads();

    bf16x8 af[4], bf[4];
#pragma unroll
    for (int mt = 0; mt < 4; ++mt)
      af[mt] = *(const bf16x8*)&Asm[(wm * 64 + mt * 16 + (lane & 15)) * 32 + (lane >> 4) * 8];
#pragma unroll
    for (int nt = 0; nt < 4; ++nt)
      bf[nt] = *(const bf16x8*)&Bsm[(wn * 64 + nt * 16 + (lane & 15)) * 32 + (lane >> 4) * 8];
#pragma unroll
    for (int mt = 0; mt < 4; ++mt)
#pragma unroll
      for (int nt = 0; nt < 4; ++nt)
        acc[mt][nt] = __builtin_amdgcn_mfma_f32_16x16x32_bf16(af[mt], bf[nt], acc[mt][nt], 0, 0, 0);
    __syncthreads();
  }

  const int cl = lane & 15, rq = (lane >> 4) * 4;
#pragma unroll
  for (int mt = 0; mt < 4; ++mt) {
    const int rbase = row0 + wm * 64 + mt * 16 + rq;
#pragma unroll
    for (int nt = 0; nt < 4; ++nt) {
      const int col = col0 + wn * 64 + nt * 16 + cl;
      const size_t sbase = ((size_t)(col >> 5) * M_PAD) * 32 + (col & 31);
#pragma unroll
      for (int i = 0; i < 4; ++i)
        C[sbase + (size_t)(rbase + i) * 32] = f2bf(acc[mt][nt][i]);
    }
  }
}

// ---------------- XCD-pinned persistent quad-per-node aggregation ----------------
// slice = HW XCC_ID & (NSLICE-1) -> each XCD's L2 holds exactly one 3.2MB table
// slice. Persistent blocks claim 64-node groups from a per-slice atomic counter.
// 4 lanes per node; lane owns 8 dims (uint4); edges sequential; no reductions.

__device__ inline void fma8(float* acc, uint4 v, float wt) {
  acc[0] += bf2f(v.x & 0xffffu) * wt;
  acc[1] += bf2f(v.x >> 16) * wt;
  acc[2] += bf2f(v.y & 0xffffu) * wt;
  acc[3] += bf2f(v.y >> 16) * wt;
  acc[4] += bf2f(v.z & 0xffffu) * wt;
  acc[5] += bf2f(v.z >> 16) * wt;
  acc[6] += bf2f(v.w & 0xffffu) * wt;
  acc[7] += bf2f(v.w >> 16) * wt;
}

template <int NSLICE, int OUT_D, bool OUT_BF16>
__global__ __launch_bounds__(256) void agg_xcd_kernel(
    const unsigned short* __restrict__ supS,  // [NSLICE][M_PAD][32]
    const unsigned long long* __restrict__ s_meta,  // {src, ew-bits} packed
    const int* __restrict__ row_ptr, const float* __restrict__ bias,
    unsigned short* __restrict__ out_bf, float* __restrict__ out_f,
    int* __restrict__ ctr, int n_groups) {
  unsigned xcc;
  asm volatile("s_getreg_b32 %0, hwreg(HW_REG_XCC_ID)" : "=s"(xcc));
  const int slice = (int)(xcc & (NSLICE - 1));
  const unsigned short* tab = supS + (size_t)slice * M_PAD * 32;
  const int tid = threadIdx.x;
  const int quad = tid >> 2;   // node within group (0..63)
  const int dimg = tid & 3;    // 8-dim octet within 32-dim slice
  __shared__ int sh_group;

  for (;;) {
    if (tid == 0) sh_group = atomicAdd(&ctr[slice], 1);
    __syncthreads();
    const int group = sh_group;
    __syncthreads();
    if (group >= n_groups) break;

    const int n = group * 64 + quad;
    const bool valid = n < N_NODES_C;
    float acc[8] = {};
    if (valid) {
      int j = row_ptr[n];
      const int end = row_ptr[n + 1];
      for (; j + 2 <= end; j += 2) {
        unsigned long long m0 = __builtin_nontemporal_load(&s_meta[j]);
        unsigned long long m1 = __builtin_nontemporal_load(&s_meta[j + 1]);
        uint4 v0 = *(const uint4*)(tab + (unsigned)(m0 & 0xffffffffu) * 32 + dimg * 8);
        uint4 v1 = *(const uint4*)(tab + (unsigned)(m1 & 0xffffffffu) * 32 + dimg * 8);
        fma8(acc, v0, __uint_as_float((unsigned)(m0 >> 32)));
        fma8(acc, v1, __uint_as_float((unsigned)(m1 >> 32)));
      }
      if (j < end) {
        unsigned long long m0 = __builtin_nontemporal_load(&s_meta[j]);
        uint4 v0 = *(const uint4*)(tab + (unsigned)(m0 & 0xffffffffu) * 32 + dimg * 8);
        fma8(acc, v0, __uint_as_float((unsigned)(m0 >> 32)));
      }
    }

    const int dbase = slice * 32 + dimg * 8;
    if (OUT_BF16) {
      unsigned short o[8];
#pragma unroll
      for (int j = 0; j < 8; ++j) {
        float v = acc[j] + bias[dbase + j];
        v = v >= 0.f ? v : NEG_SLOPE * v;
        o[j] = f2bf(v);
      }
      uint4 pk;
      pk.x = o[0] | ((unsigned)o[1] << 16);
      pk.y = o[2] | ((unsigned)o[3] << 16);
      pk.z = o[4] | ((unsigned)o[5] << 16);
      pk.w = o[6] | ((unsigned)o[7] << 16);
      *(uint4*)(out_bf + (size_t)n * OUT_D + dbase) = pk;
    } else if (valid) {
      float r[8];
#pragma unroll
      for (int j = 0; j < 8; ++j) {
        float v = acc[j] + bias[dbase + j];
        r[j] = v >= 0.f ? v : NEG_SLOPE * v;
      }
      *(float4*)(out_f + (size_t)n * OUT_D + dbase) = make_float4(r[0], r[1], r[2], r[3]);
      *(float4*)(out_f + (size_t)n * OUT_D + dbase + 4) = make_float4(r[4], r[5], r[6], r[7]);
    }
  }
}

// ---------------- launch ----------------

extern "C" void kernel_launch(void* const* d_in, const int* in_sizes, int n_in,
                              void* d_out, int out_size, void* d_ws, size_t ws_size,
                              hipStream_t stream) {
  const float* x  = (const float*)d_in[0];   // [50000,256]
  const float* w1 = (const float*)d_in[1];   // [256,256]
  const float* b1 = (const float*)d_in[2];   // [256]
  const float* w2 = (const float*)d_in[3];   // [256,128]
  const float* b2 = (const float*)d_in[4];   // [128]
  const int*   src = (const int*)d_in[5];    // [800000]
  const int*   dst = (const int*)d_in[6];    // [800000]
  const float* ew  = (const float*)d_in[7];  // [800000]
  float* out = (float*)d_out;                // [50000,128]

  unsigned short* xb   = (unsigned short*)d_ws;              // M_PAD*256
  unsigned short* a2b  = xb + (size_t)M_PAD * 256;           // M_PAD*256
  unsigned short* sup1 = a2b + (size_t)M_PAD * 256;          // 8 x [M_PAD][32]
  unsigned short* sup2 = sup1 + (size_t)M_PAD * 256;         // 4 x [M_PAD][32]
  unsigned short* w1T  = sup2 + (size_t)M_PAD * 128;         // 256*256
  unsigned short* w2T  = w1T + 256 * 256;                    // 128*256
  int* counts  = (int*)(w2T + 128 * 256);                    // 50000
  int* cursor  = counts + N_NODES_C;                         // 50000
  int* row_ptr = cursor + N_NODES_C;                         // 50001
  int* partial = row_ptr + (N_NODES_C + 1);                  // 50000
  int* blk_sums= partial + N_NODES_C;                        // 256
  int* blk_off = blk_sums + 256;                             // 256
  int* ctr1    = blk_off + 256;                              // 8
  int* ctr2    = ctr1 + 8;                                   // 8 (use 4)
  uint2* s_meta = (uint2*)(ctr2 + 8);                        // 800000 * 8B

  const int EB = (N_EDGES_C + 255) / 256;

  // preprocessing
  hipMemsetAsync(counts, 0, N_NODES_C * sizeof(int), stream);
  hipMemsetAsync(ctr1, 0, 16 * sizeof(int), stream);
  pre_kernel<<<NB_PRE, 256, 0, stream>>>(x, w1, w2, dst, xb, w1T, w2T, counts);

  // CSR scan + fill
  scan_phase_a<<<N_SCAN_BLKS, 256, 0, stream>>>(counts, partial, blk_sums);
  scan_phase_b<<<1, 256, 0, stream>>>(blk_sums, blk_off);
  scan_phase_c<<<N_SCAN_BLKS, 256, 0, stream>>>(partial, blk_off, row_ptr, cursor);
  fill_kernel<<<EB, 256, 0, stream>>>(src, dst, ew, cursor, s_meta);

  const int NGROUPS = M_PAD / 64;  // 782 (also covers 50000 for layer 2)

  // layer 1
  gemm_bf16_kernel<<<dim3(2, M_PAD / 128), 256, 0, stream>>>(xb, w1T, sup1, 256);
  agg_xcd_kernel<8, 256, true><<<2048, 256, 0, stream>>>(
      sup1, (const unsigned long long*)s_meta, row_ptr, b1, a2b, nullptr, ctr1, NGROUPS);

  // layer 2
  gemm_bf16_kernel<<<dim3(1, M_PAD / 128), 256, 0, stream>>>(a2b, w2T, sup2, 128);
  agg_xcd_kernel<4, 128, false><<<2048, 256, 0, stream>>>(
      sup2, (const unsigned long long*)s_meta, row_ptr, b2, nullptr, out, ctr2, NGROUPS);
}

// Round 9
// 434.126 us; speedup vs baseline: 1.1089x; 1.1089x over previous
//
#include <hip/hip_runtime.h>

#define NEG_SLOPE 0.01f

constexpr int N_NODES_C = 50000;
constexpr int N_EDGES_C = 800000;
constexpr int M_PAD = 50048;  // 391 * 128

typedef short bf16x8 __attribute__((ext_vector_type(8)));
typedef float f32x4 __attribute__((ext_vector_type(4)));

__device__ inline unsigned short f2bf(float f) {
  unsigned int u = __float_as_uint(f);
  u += 0x7FFF + ((u >> 16) & 1);  // round-to-nearest-even
  return (unsigned short)(u >> 16);
}
__device__ inline float bf2f(unsigned int h16) {
  return __uint_as_float(h16 << 16);
}

// ---------------- fused preprocessing ----------------
constexpr int NB_CONVX = (M_PAD * 32) / 256;          // 6256
constexpr int NB_W1 = (256 * 256) / 256;              // 256
constexpr int NB_W2 = (256 * 128) / 256;              // 128
constexpr int NB_HIST = N_EDGES_C / 256;              // 3125
constexpr int NB_PRE = NB_CONVX + NB_W1 + NB_W2 + NB_HIST;

__global__ __launch_bounds__(256) void pre_kernel(
    const float* __restrict__ x, const float* __restrict__ w1,
    const float* __restrict__ w2, const int* __restrict__ dst,
    unsigned short* __restrict__ xb, unsigned short* __restrict__ w1T,
    unsigned short* __restrict__ w2T, int* __restrict__ counts) {
  const int bx = blockIdx.x;
  const int tid = threadIdx.x;
  if (bx < NB_CONVX) {
    int idx = bx * 256 + tid;
    int row = idx >> 5;
    int c8 = (idx & 31) << 3;
    uint4 v;
    if (row < N_NODES_C) {
      const float4* p = (const float4*)(x + (size_t)row * 256 + c8);
      float4 a = p[0], b = p[1];
      v.x = f2bf(a.x) | ((unsigned)f2bf(a.y) << 16);
      v.y = f2bf(a.z) | ((unsigned)f2bf(a.w) << 16);
      v.z = f2bf(b.x) | ((unsigned)f2bf(b.y) << 16);
      v.w = f2bf(b.z) | ((unsigned)f2bf(b.w) << 16);
    } else {
      v = make_uint4(0, 0, 0, 0);
    }
    *(uint4*)(xb + (size_t)row * 256 + c8) = v;
  } else if (bx < NB_CONVX + NB_W1) {
    int idx = (bx - NB_CONVX) * 256 + tid;  // over [N=256][K=256]
    int n = idx >> 8, k = idx & 255;
    w1T[idx] = f2bf(w1[(size_t)k * 256 + n]);
  } else if (bx < NB_CONVX + NB_W1 + NB_W2) {
    int idx = (bx - NB_CONVX - NB_W1) * 256 + tid;  // over [N=128][K=256]
    int n = idx >> 8, k = idx & 255;
    w2T[idx] = f2bf(w2[(size_t)k * 128 + n]);
  } else {
    int e = (bx - NB_CONVX - NB_W1 - NB_W2) * 256 + tid;
    atomicAdd(&counts[dst[e]], 1);
  }
}

// ---------------- hierarchical scan ----------------
constexpr int N_SCAN_BLKS = (N_NODES_C + 255) / 256;  // 196

__global__ __launch_bounds__(256) void scan_phase_a(const int* __restrict__ counts,
                                                    int* __restrict__ partial,
                                                    int* __restrict__ blk_sums) {
  __shared__ int s[256];
  const int t = threadIdx.x;
  const int i = blockIdx.x * 256 + t;
  const int v = (i < N_NODES_C) ? counts[i] : 0;
  s[t] = v;
  __syncthreads();
  for (int off = 1; off < 256; off <<= 1) {
    int u = (t >= off) ? s[t - off] : 0;
    __syncthreads();
    s[t] += u;
    __syncthreads();
  }
  if (i < N_NODES_C) partial[i] = s[t] - v;
  if (t == 255) blk_sums[blockIdx.x] = s[255];
}

__global__ __launch_bounds__(256) void scan_phase_b(const int* __restrict__ blk_sums,
                                                    int* __restrict__ blk_off) {
  __shared__ int s[256];
  const int t = threadIdx.x;
  const int v = (t < N_SCAN_BLKS) ? blk_sums[t] : 0;
  s[t] = v;
  __syncthreads();
  for (int off = 1; off < 256; off <<= 1) {
    int u = (t >= off) ? s[t - off] : 0;
    __syncthreads();
    s[t] += u;
    __syncthreads();
  }
  if (t < N_SCAN_BLKS) blk_off[t] = s[t] - v;
}

__global__ __launch_bounds__(256) void scan_phase_c(const int* __restrict__ partial,
                                                    const int* __restrict__ blk_off,
                                                    int* __restrict__ row_ptr,
                                                    int* __restrict__ cursor) {
  const int i = blockIdx.x * 256 + threadIdx.x;
  if (i < N_NODES_C) {
    const int r = partial[i] + blk_off[blockIdx.x];
    row_ptr[i] = r;
    cursor[i] = r;
  }
  if (i == 0) row_ptr[N_NODES_C] = N_EDGES_C;
}

__global__ __launch_bounds__(256) void fill_kernel(const int* __restrict__ src,
                                                   const int* __restrict__ dst,
                                                   const float* __restrict__ ew,
                                                   int* __restrict__ cursor,
                                                   uint2* __restrict__ s_meta) {
  int e = blockIdx.x * 256 + threadIdx.x;
  if (e < N_EDGES_C) {
    int p = atomicAdd(&cursor[dst[e]], 1);
    uint2 m;
    m.x = (unsigned)src[e];
    m.y = __float_as_uint(ew[e]);
    s_meta[p] = m;
  }
}

// ---------------- bf16 MFMA GEMM with SLICED output ----------------

#define GLOAD_LDS16(g, l)                                              \
  __builtin_amdgcn_global_load_lds(                                    \
      (__attribute__((address_space(1))) void*)(g),                    \
      (__attribute__((address_space(3))) void*)(l), 16, 0, 0)

__global__ __launch_bounds__(256) void gemm_bf16_kernel(
    const unsigned short* __restrict__ A,   // [M_PAD][256] bf16
    const unsigned short* __restrict__ BT,  // [N][256] bf16
    unsigned short* __restrict__ C,         // [N/32][M_PAD][32] bf16 sliced
    int N) {
  constexpr int K = 256;
  __shared__ short Asm[128 * 32];
  __shared__ short Bsm[128 * 32];
  const int tid = threadIdx.x;
  const int lane = tid & 63, wave = tid >> 6;
  const int wm = wave & 1, wn = wave >> 1;
  const int row0 = blockIdx.y * 128, col0 = blockIdx.x * 128;

  const int ch0 = wave * 2, ch1 = wave * 2 + 1;
  const int o0 = ch0 * 512 + lane * 8;
  const int o1 = ch1 * 512 + lane * 8;
  const int r0 = o0 >> 5, c0 = o0 & 31;
  const int r1 = o1 >> 5, c1 = o1 & 31;

  f32x4 acc[4][4] = {};

  for (int k0 = 0; k0 < K; k0 += 32) {
    GLOAD_LDS16(A + (size_t)(row0 + r0) * K + k0 + c0, &Asm[ch0 * 512]);
    GLOAD_LDS16(A + (size_t)(row0 + r1) * K + k0 + c1, &Asm[ch1 * 512]);
    GLOAD_LDS16(BT + (size_t)(col0 + r0) * K + k0 + c0, &Bsm[ch0 * 512]);
    GLOAD_LDS16(BT + (size_t)(col0 + r1) * K + k0 + c1, &Bsm[ch1 * 512]);
    __builtin_amdgcn_s_waitcnt(0);
    __syncthreads();

    bf16x8 af[4], bf[4];
#pragma unroll
    for (int mt = 0; mt < 4; ++mt)
      af[mt] = *(const bf16x8*)&Asm[(wm * 64 + mt * 16 + (lane & 15)) * 32 + (lane >> 4) * 8];
#pragma unroll
    for (int nt = 0; nt < 4; ++nt)
      bf[nt] = *(const bf16x8*)&Bsm[(wn * 64 + nt * 16 + (lane & 15)) * 32 + (lane >> 4) * 8];
#pragma unroll
    for (int mt = 0; mt < 4; ++mt)
#pragma unroll
      for (int nt = 0; nt < 4; ++nt)
        acc[mt][nt] = __builtin_amdgcn_mfma_f32_16x16x32_bf16(af[mt], bf[nt], acc[mt][nt], 0, 0, 0);
    __syncthreads();
  }

  const int cl = lane & 15, rq = (lane >> 4) * 4;
#pragma unroll
  for (int mt = 0; mt < 4; ++mt) {
    const int rbase = row0 + wm * 64 + mt * 16 + rq;
#pragma unroll
    for (int nt = 0; nt < 4; ++nt) {
      const int col = col0 + wn * 64 + nt * 16 + cl;
      const size_t sbase = ((size_t)(col >> 5) * M_PAD) * 32 + (col & 31);
#pragma unroll
      for (int i = 0; i < 4; ++i)
        C[sbase + (size_t)(rbase + i) * 32] = f2bf(acc[mt][nt][i]);
    }
  }
}

// ---------------- XCD-pinned persistent quad-per-node aggregation ----------------
// slice = HW XCC_ID & (NSLICE-1); persistent blocks claim 64-node groups from a
// per-slice atomic counter. 4 lanes per node; lane owns 8 dims; edges sequential.
// Meta loads are PLAIN CACHED loads (R8's nontemporal loads caused 8x fetch
// amplification + full-latency serial chain -> reverted).

__device__ inline void fma8(float* acc, uint4 v, float wt) {
  acc[0] += bf2f(v.x & 0xffffu) * wt;
  acc[1] += bf2f(v.x >> 16) * wt;
  acc[2] += bf2f(v.y & 0xffffu) * wt;
  acc[3] += bf2f(v.y >> 16) * wt;
  acc[4] += bf2f(v.z & 0xffffu) * wt;
  acc[5] += bf2f(v.z >> 16) * wt;
  acc[6] += bf2f(v.w & 0xffffu) * wt;
  acc[7] += bf2f(v.w >> 16) * wt;
}

template <int NSLICE, int OUT_D, bool OUT_BF16>
__global__ __launch_bounds__(256) void agg_xcd_kernel(
    const unsigned short* __restrict__ supS,  // [NSLICE][M_PAD][32]
    const uint2* __restrict__ s_meta,         // {src, ew-bits}
    const int* __restrict__ row_ptr, const float* __restrict__ bias,
    unsigned short* __restrict__ out_bf, float* __restrict__ out_f,
    int* __restrict__ ctr, int n_groups) {
  unsigned xcc;
  asm volatile("s_getreg_b32 %0, hwreg(HW_REG_XCC_ID)" : "=s"(xcc));
  const int slice = (int)(xcc & (NSLICE - 1));
  const unsigned short* tab = supS + (size_t)slice * M_PAD * 32;
  const int tid = threadIdx.x;
  const int quad = tid >> 2;   // node within group (0..63)
  const int dimg = tid & 3;    // 8-dim octet within 32-dim slice
  __shared__ int sh_group;

  for (;;) {
    if (tid == 0) sh_group = atomicAdd(&ctr[slice], 1);
    __syncthreads();
    const int group = sh_group;
    __syncthreads();
    if (group >= n_groups) break;

    const int n = group * 64 + quad;
    const bool valid = n < N_NODES_C;
    float acc[8] = {};
    if (valid) {
      int j = row_ptr[n];
      const int end = row_ptr[n + 1];
      for (; j + 2 <= end; j += 2) {
        uint2 m0 = s_meta[j];
        uint2 m1 = s_meta[j + 1];
        uint4 v0 = *(const uint4*)(tab + (size_t)m0.x * 32 + dimg * 8);
        uint4 v1 = *(const uint4*)(tab + (size_t)m1.x * 32 + dimg * 8);
        fma8(acc, v0, __uint_as_float(m0.y));
        fma8(acc, v1, __uint_as_float(m1.y));
      }
      if (j < end) {
        uint2 m0 = s_meta[j];
        uint4 v0 = *(const uint4*)(tab + (size_t)m0.x * 32 + dimg * 8);
        fma8(acc, v0, __uint_as_float(m0.y));
      }
    }

    const int dbase = slice * 32 + dimg * 8;
    if (OUT_BF16) {
      unsigned short o[8];
#pragma unroll
      for (int j = 0; j < 8; ++j) {
        float v = acc[j] + bias[dbase + j];
        v = v >= 0.f ? v : NEG_SLOPE * v;
        o[j] = f2bf(v);
      }
      uint4 pk;
      pk.x = o[0] | ((unsigned)o[1] << 16);
      pk.y = o[2] | ((unsigned)o[3] << 16);
      pk.z = o[4] | ((unsigned)o[5] << 16);
      pk.w = o[6] | ((unsigned)o[7] << 16);
      *(uint4*)(out_bf + (size_t)n * OUT_D + dbase) = pk;
    } else if (valid) {
      float r[8];
#pragma unroll
      for (int j = 0; j < 8; ++j) {
        float v = acc[j] + bias[dbase + j];
        r[j] = v >= 0.f ? v : NEG_SLOPE * v;
      }
      *(float4*)(out_f + (size_t)n * OUT_D + dbase) = make_float4(r[0], r[1], r[2], r[3]);
      *(float4*)(out_f + (size_t)n * OUT_D + dbase + 4) = make_float4(r[4], r[5], r[6], r[7]);
    }
  }
}

// ---------------- launch ----------------

extern "C" void kernel_launch(void* const* d_in, const int* in_sizes, int n_in,
                              void* d_out, int out_size, void* d_ws, size_t ws_size,
                              hipStream_t stream) {
  const float* x  = (const float*)d_in[0];   // [50000,256]
  const float* w1 = (const float*)d_in[1];   // [256,256]
  const float* b1 = (const float*)d_in[2];   // [256]
  const float* w2 = (const float*)d_in[3];   // [256,128]
  const float* b2 = (const float*)d_in[4];   // [128]
  const int*   src = (const int*)d_in[5];    // [800000]
  const int*   dst = (const int*)d_in[6];    // [800000]
  const float* ew  = (const float*)d_in[7];  // [800000]
  float* out = (float*)d_out;                // [50000,128]

  unsigned short* xb   = (unsigned short*)d_ws;              // M_PAD*256
  unsigned short* a2b  = xb + (size_t)M_PAD * 256;           // M_PAD*256
  unsigned short* sup1 = a2b + (size_t)M_PAD * 256;          // 8 x [M_PAD][32]
  unsigned short* sup2 = sup1 + (size_t)M_PAD * 256;         // 4 x [M_PAD][32]
  unsigned short* w1T  = sup2 + (size_t)M_PAD * 128;         // 256*256
  unsigned short* w2T  = w1T + 256 * 256;                    // 128*256
  int* counts  = (int*)(w2T + 128 * 256);                    // 50000
  int* cursor  = counts + N_NODES_C;                         // 50000
  int* row_ptr = cursor + N_NODES_C;                         // 50001
  int* partial = row_ptr + (N_NODES_C + 1);                  // 50000
  int* blk_sums= partial + N_NODES_C;                        // 256
  int* blk_off = blk_sums + 256;                             // 256
  int* ctr1    = blk_off + 256;                              // 8
  int* ctr2    = ctr1 + 8;                                   // 8 (use 4)
  uint2* s_meta = (uint2*)(ctr2 + 8);                        // 800000 * 8B

  const int EB = (N_EDGES_C + 255) / 256;

  // preprocessing
  hipMemsetAsync(counts, 0, N_NODES_C * sizeof(int), stream);
  hipMemsetAsync(ctr1, 0, 16 * sizeof(int), stream);
  pre_kernel<<<NB_PRE, 256, 0, stream>>>(x, w1, w2, dst, xb, w1T, w2T, counts);

  // CSR scan + fill
  scan_phase_a<<<N_SCAN_BLKS, 256, 0, stream>>>(counts, partial, blk_sums);
  scan_phase_b<<<1, 256, 0, stream>>>(blk_sums, blk_off);
  scan_phase_c<<<N_SCAN_BLKS, 256, 0, stream>>>(partial, blk_off, row_ptr, cursor);
  fill_kernel<<<EB, 256, 0, stream>>>(src, dst, ew, cursor, s_meta);

  const int NGROUPS = M_PAD / 64;  // 782 (also covers 50000 for layer 2)

  // layer 1
  gemm_bf16_kernel<<<dim3(2, M_PAD / 128), 256, 0, stream>>>(xb, w1T, sup1, 256);
  agg_xcd_kernel<8, 256, true><<<2048, 256, 0, stream>>>(
      sup1, s_meta, row_ptr, b1, a2b, nullptr, ctr1, NGROUPS);

  // layer 2
  gemm_bf16_kernel<<<dim3(1, M_PAD / 128), 256, 0, stream>>>(a2b, w2T, sup2, 128);
  agg_xcd_kernel<4, 128, false><<<2048, 256, 0, stream>>>(
      sup2, s_meta, row_ptr, b2, nullptr, out, ctr2, NGROUPS);
}

// Round 10
// 305.693 us; speedup vs baseline: 1.5748x; 1.4201x over previous
//
#include <hip/hip_runtime.h>

#define NEG_SLOPE 0.01f

constexpr int N_NODES_C = 50000;
constexpr int N_EDGES_C = 800000;
constexpr int M_PAD = 50048;  // 391 * 128

typedef short bf16x8 __attribute__((ext_vector_type(8)));
typedef float f32x4 __attribute__((ext_vector_type(4)));

__device__ inline unsigned short f2bf(float f) {
  unsigned int u = __float_as_uint(f);
  u += 0x7FFF + ((u >> 16) & 1);  // round-to-nearest-even
  return (unsigned short)(u >> 16);
}
__device__ inline float bf2f(unsigned int h16) {
  return __uint_as_float(h16 << 16);
}

// ---------------- fused preprocessing ----------------
constexpr int NB_CONVX = (M_PAD * 32) / 256;          // 6256
constexpr int NB_W1 = (256 * 256) / 256;              // 256
constexpr int NB_W2 = (256 * 128) / 256;              // 128
constexpr int NB_HIST = N_EDGES_C / 256;              // 3125
constexpr int NB_PRE = NB_CONVX + NB_W1 + NB_W2 + NB_HIST;

__global__ __launch_bounds__(256) void pre_kernel(
    const float* __restrict__ x, const float* __restrict__ w1,
    const float* __restrict__ w2, const int* __restrict__ dst,
    unsigned short* __restrict__ xb, unsigned short* __restrict__ w1T,
    unsigned short* __restrict__ w2T, int* __restrict__ counts) {
  const int bx = blockIdx.x;
  const int tid = threadIdx.x;
  if (bx < NB_CONVX) {
    int idx = bx * 256 + tid;
    int row = idx >> 5;
    int c8 = (idx & 31) << 3;
    uint4 v;
    if (row < N_NODES_C) {
      const float4* p = (const float4*)(x + (size_t)row * 256 + c8);
      float4 a = p[0], b = p[1];
      v.x = f2bf(a.x) | ((unsigned)f2bf(a.y) << 16);
      v.y = f2bf(a.z) | ((unsigned)f2bf(a.w) << 16);
      v.z = f2bf(b.x) | ((unsigned)f2bf(b.y) << 16);
      v.w = f2bf(b.z) | ((unsigned)f2bf(b.w) << 16);
    } else {
      v = make_uint4(0, 0, 0, 0);
    }
    *(uint4*)(xb + (size_t)row * 256 + c8) = v;
  } else if (bx < NB_CONVX + NB_W1) {
    int idx = (bx - NB_CONVX) * 256 + tid;  // over [N=256][K=256]
    int n = idx >> 8, k = idx & 255;
    w1T[idx] = f2bf(w1[(size_t)k * 256 + n]);
  } else if (bx < NB_CONVX + NB_W1 + NB_W2) {
    int idx = (bx - NB_CONVX - NB_W1) * 256 + tid;  // over [N=128][K=256]
    int n = idx >> 8, k = idx & 255;
    w2T[idx] = f2bf(w2[(size_t)k * 128 + n]);
  } else {
    int e = (bx - NB_CONVX - NB_W1 - NB_W2) * 256 + tid;
    atomicAdd(&counts[dst[e]], 1);
  }
}

// ---------------- hierarchical scan (2 launches) ----------------
constexpr int N_SCAN_BLKS = (N_NODES_C + 255) / 256;  // 196

__global__ __launch_bounds__(256) void scan_phase_a(const int* __restrict__ counts,
                                                    int* __restrict__ partial,
                                                    int* __restrict__ blk_sums) {
  __shared__ int s[256];
  const int t = threadIdx.x;
  const int i = blockIdx.x * 256 + t;
  const int v = (i < N_NODES_C) ? counts[i] : 0;
  s[t] = v;
  __syncthreads();
  for (int off = 1; off < 256; off <<= 1) {
    int u = (t >= off) ? s[t - off] : 0;
    __syncthreads();
    s[t] += u;
    __syncthreads();
  }
  if (i < N_NODES_C) partial[i] = s[t] - v;
  if (t == 255) blk_sums[blockIdx.x] = s[255];
}

// each block redundantly scans the 196 block sums, then adds its own offset
__global__ __launch_bounds__(256) void scan_phase_bc(const int* __restrict__ partial,
                                                     const int* __restrict__ blk_sums,
                                                     int* __restrict__ row_ptr,
                                                     int* __restrict__ cursor) {
  __shared__ int s[256];
  __shared__ int blk_excl;
  const int t = threadIdx.x;
  const int v = (t < N_SCAN_BLKS) ? blk_sums[t] : 0;
  s[t] = v;
  __syncthreads();
  for (int off = 1; off < 256; off <<= 1) {
    int u = (t >= off) ? s[t - off] : 0;
    __syncthreads();
    s[t] += u;
    __syncthreads();
  }
  if (t == (int)blockIdx.x) blk_excl = s[t] - v;  // this block's exclusive offset
  __syncthreads();
  const int i = blockIdx.x * 256 + t;
  if (i < N_NODES_C) {
    const int r = partial[i] + blk_excl;
    row_ptr[i] = r;
    cursor[i] = r;
  }
  if (i == 0) row_ptr[N_NODES_C] = N_EDGES_C;
}

// ---------------- shared GEMM tile (device fn) ----------------
// C_sliced[slice][M_PAD][32] where slice = col/32

#define GLOAD_LDS16(g, l)                                              \
  __builtin_amdgcn_global_load_lds(                                    \
      (__attribute__((address_space(1))) void*)(g),                    \
      (__attribute__((address_space(3))) void*)(l), 16, 0, 0)

__device__ __forceinline__ void gemm_tile(
    const unsigned short* __restrict__ A,   // [M_PAD][256] bf16
    const unsigned short* __restrict__ BT,  // [N][256] bf16
    unsigned short* __restrict__ C,         // [N/32][M_PAD][32] sliced
    int N, int row0, int col0, short* Asm, short* Bsm) {
  constexpr int K = 256;
  const int tid = threadIdx.x;
  const int lane = tid & 63, wave = tid >> 6;
  const int wm = wave & 1, wn = wave >> 1;

  const int ch0 = wave * 2, ch1 = wave * 2 + 1;
  const int o0 = ch0 * 512 + lane * 8;
  const int o1 = ch1 * 512 + lane * 8;
  const int r0 = o0 >> 5, c0 = o0 & 31;
  const int r1 = o1 >> 5, c1 = o1 & 31;

  f32x4 acc[4][4] = {};

  for (int k0 = 0; k0 < K; k0 += 32) {
    GLOAD_LDS16(A + (size_t)(row0 + r0) * K + k0 + c0, &Asm[ch0 * 512]);
    GLOAD_LDS16(A + (size_t)(row0 + r1) * K + k0 + c1, &Asm[ch1 * 512]);
    GLOAD_LDS16(BT + (size_t)(col0 + r0) * K + k0 + c0, &Bsm[ch0 * 512]);
    GLOAD_LDS16(BT + (size_t)(col0 + r1) * K + k0 + c1, &Bsm[ch1 * 512]);
    __builtin_amdgcn_s_waitcnt(0);
    __syncthreads();

    bf16x8 af[4], bf[4];
#pragma unroll
    for (int mt = 0; mt < 4; ++mt)
      af[mt] = *(const bf16x8*)&Asm[(wm * 64 + mt * 16 + (lane & 15)) * 32 + (lane >> 4) * 8];
#pragma unroll
    for (int nt = 0; nt < 4; ++nt)
      bf[nt] = *(const bf16x8*)&Bsm[(wn * 64 + nt * 16 + (lane & 15)) * 32 + (lane >> 4) * 8];
#pragma unroll
    for (int mt = 0; mt < 4; ++mt)
#pragma unroll
      for (int nt = 0; nt < 4; ++nt)
        acc[mt][nt] = __builtin_amdgcn_mfma_f32_16x16x32_bf16(af[mt], bf[nt], acc[mt][nt], 0, 0, 0);
    __syncthreads();
  }

  const int cl = lane & 15, rq = (lane >> 4) * 4;
#pragma unroll
  for (int mt = 0; mt < 4; ++mt) {
    const int rbase = row0 + wm * 64 + mt * 16 + rq;
#pragma unroll
    for (int nt = 0; nt < 4; ++nt) {
      const int col = col0 + wn * 64 + nt * 16 + cl;
      const size_t sbase = ((size_t)(col >> 5) * M_PAD) * 32 + (col & 31);
#pragma unroll
      for (int i = 0; i < 4; ++i)
        C[sbase + (size_t)(rbase + i) * 32] = f2bf(acc[mt][nt][i]);
    }
  }
}

// ---------------- fused fill + gemm1 ----------------
// blocks [0, NB_GEMM1): gemm1 tiles; [NB_GEMM1, +NB_FILL): CSR bucket fill.
// meta packed 4B: src(u16) | bf16(ew)<<16
constexpr int NB_GEMM1 = 2 * (M_PAD / 128);           // 782
constexpr int NB_FILL = (N_EDGES_C + 255) / 256;      // 3125

__global__ __launch_bounds__(256) void fill_gemm1_kernel(
    const unsigned short* __restrict__ A, const unsigned short* __restrict__ BT,
    unsigned short* __restrict__ C, const int* __restrict__ src,
    const int* __restrict__ dst, const float* __restrict__ ew,
    int* __restrict__ cursor, unsigned* __restrict__ s_meta) {
  __shared__ short Asm[128 * 32];
  __shared__ short Bsm[128 * 32];
  const int b = blockIdx.x;
  if (b < NB_GEMM1) {
    gemm_tile(A, BT, C, 256, (b >> 1) * 128, (b & 1) * 128, Asm, Bsm);
  } else {
    int e = (b - NB_GEMM1) * 256 + threadIdx.x;
    if (e < N_EDGES_C) {
      int p = atomicAdd(&cursor[dst[e]], 1);
      s_meta[p] = (unsigned)src[e] | ((unsigned)f2bf(ew[e]) << 16);
    }
  }
}

__global__ __launch_bounds__(256) void gemm2_kernel(
    const unsigned short* __restrict__ A, const unsigned short* __restrict__ BT,
    unsigned short* __restrict__ C) {
  __shared__ short Asm[128 * 32];
  __shared__ short Bsm[128 * 32];
  gemm_tile(A, BT, C, 128, blockIdx.x * 128, 0, Asm, Bsm);
}

// ---------------- lite sliced aggregation ----------------
// ONE WAVE per block (64 thr) = 16 quad-nodes; slice = bx & (NSLICE-1) with
// slice-innermost ordering (tiny uniform blocks -> round-robin XCD pinning,
// narrow concurrent meta window -> table slice stays L2-resident; R6 evidence).
// 4 lanes per node; lane owns 8 dims; edges sequential; no reductions.

__device__ inline void fma8(float* acc, uint4 v, float wt) {
  acc[0] += bf2f(v.x & 0xffffu) * wt;
  acc[1] += bf2f(v.x >> 16) * wt;
  acc[2] += bf2f(v.y & 0xffffu) * wt;
  acc[3] += bf2f(v.y >> 16) * wt;
  acc[4] += bf2f(v.z & 0xffffu) * wt;
  acc[5] += bf2f(v.z >> 16) * wt;
  acc[6] += bf2f(v.w & 0xffffu) * wt;
  acc[7] += bf2f(v.w >> 16) * wt;
}

template <int NSLICE, int OUT_D, bool OUT_BF16>
__global__ __launch_bounds__(64) void agg_lite_kernel(
    const unsigned short* __restrict__ supS,  // [NSLICE][M_PAD][32]
    const unsigned* __restrict__ s_meta,      // src u16 | bf16(ew) << 16
    const int* __restrict__ row_ptr, const float* __restrict__ bias,
    unsigned short* __restrict__ out_bf, float* __restrict__ out_f, int n_total) {
  const int bx = blockIdx.x;
  const int slice = bx & (NSLICE - 1);
  const int group = bx / NSLICE;
  const int lane = threadIdx.x;  // 0..63
  const int quad = lane >> 2;    // node within group (0..15)
  const int dimg = lane & 3;     // 8-dim octet within 32-dim slice
  const int n = group * 16 + quad;
  if (n >= n_total) return;
  const bool valid = n < N_NODES_C;
  const unsigned short* tab = supS + (size_t)slice * M_PAD * 32;

  float acc[8] = {};
  if (valid) {
    int j = row_ptr[n];
    const int end = row_ptr[n + 1];
    for (; j + 2 <= end; j += 2) {
      unsigned m0 = s_meta[j];
      unsigned m1 = s_meta[j + 1];
      uint4 v0 = *(const uint4*)(tab + (m0 & 0xffffu) * 32 + dimg * 8);
      uint4 v1 = *(const uint4*)(tab + (m1 & 0xffffu) * 32 + dimg * 8);
      fma8(acc, v0, bf2f(m0 >> 16));
      fma8(acc, v1, bf2f(m1 >> 16));
    }
    if (j < end) {
      unsigned m0 = s_meta[j];
      uint4 v0 = *(const uint4*)(tab + (m0 & 0xffffu) * 32 + dimg * 8);
      fma8(acc, v0, bf2f(m0 >> 16));
    }
  }

  const int dbase = slice * 32 + dimg * 8;
  if (OUT_BF16) {
    unsigned short o[8];
#pragma unroll
    for (int j = 0; j < 8; ++j) {
      if (valid) {
        float v = acc[j] + bias[dbase + j];
        v = v >= 0.f ? v : NEG_SLOPE * v;
        o[j] = f2bf(v);
      } else {
        o[j] = 0;
      }
    }
    uint4 pk;
    pk.x = o[0] | ((unsigned)o[1] << 16);
    pk.y = o[2] | ((unsigned)o[3] << 16);
    pk.z = o[4] | ((unsigned)o[5] << 16);
    pk.w = o[6] | ((unsigned)o[7] << 16);
    *(uint4*)(out_bf + (size_t)n * OUT_D + dbase) = pk;
  } else if (valid) {
    float r[8];
#pragma unroll
    for (int j = 0; j < 8; ++j) {
      float v = acc[j] + bias[dbase + j];
      r[j] = v >= 0.f ? v : NEG_SLOPE * v;
    }
    *(float4*)(out_f + (size_t)n * OUT_D + dbase) = make_float4(r[0], r[1], r[2], r[3]);
    *(float4*)(out_f + (size_t)n * OUT_D + dbase + 4) = make_float4(r[4], r[5], r[6], r[7]);
  }
}

// ---------------- launch ----------------

extern "C" void kernel_launch(void* const* d_in, const int* in_sizes, int n_in,
                              void* d_out, int out_size, void* d_ws, size_t ws_size,
                              hipStream_t stream) {
  const float* x  = (const float*)d_in[0];   // [50000,256]
  const float* w1 = (const float*)d_in[1];   // [256,256]
  const float* b1 = (const float*)d_in[2];   // [256]
  const float* w2 = (const float*)d_in[3];   // [256,128]
  const float* b2 = (const float*)d_in[4];   // [128]
  const int*   src = (const int*)d_in[5];    // [800000]
  const int*   dst = (const int*)d_in[6];    // [800000]
  const float* ew  = (const float*)d_in[7];  // [800000]
  float* out = (float*)d_out;                // [50000,128]

  unsigned short* xb   = (unsigned short*)d_ws;              // M_PAD*256
  unsigned short* a2b  = xb + (size_t)M_PAD * 256;           // M_PAD*256
  unsigned short* sup1 = a2b + (size_t)M_PAD * 256;          // 8 x [M_PAD][32]
  unsigned short* sup2 = sup1 + (size_t)M_PAD * 256;         // 4 x [M_PAD][32]
  unsigned short* w1T  = sup2 + (size_t)M_PAD * 128;         // 256*256
  unsigned short* w2T  = w1T + 256 * 256;                    // 128*256
  int* counts  = (int*)(w2T + 128 * 256);                    // 50000
  int* cursor  = counts + N_NODES_C;                         // 50000
  int* row_ptr = cursor + N_NODES_C;                         // 50001
  int* partial = row_ptr + (N_NODES_C + 1);                  // 50000
  int* blk_sums= partial + N_NODES_C;                        // 256
  unsigned* s_meta = (unsigned*)(blk_sums + 256);            // 800000 * 4B

  // preprocessing: zero counts, then fused {conv_x, w1T, w2T, histogram}
  hipMemsetAsync(counts, 0, N_NODES_C * sizeof(int), stream);
  pre_kernel<<<NB_PRE, 256, 0, stream>>>(x, w1, w2, dst, xb, w1T, w2T, counts);

  // CSR scan
  scan_phase_a<<<N_SCAN_BLKS, 256, 0, stream>>>(counts, partial, blk_sums);
  scan_phase_bc<<<N_SCAN_BLKS, 256, 0, stream>>>(partial, blk_sums, row_ptr, cursor);

  // fused: CSR bucket fill + gemm1 (independent work, one dispatch)
  fill_gemm1_kernel<<<NB_GEMM1 + NB_FILL, 256, 0, stream>>>(
      xb, w1T, sup1, src, dst, ew, cursor, s_meta);

  // layer-1 aggregation -> a2b (bf16, lrelu+bias fused)
  agg_lite_kernel<8, 256, true><<<(M_PAD / 16) * 8, 64, 0, stream>>>(
      sup1, s_meta, row_ptr, b1, a2b, nullptr, M_PAD);

  // layer 2
  gemm2_kernel<<<M_PAD / 128, 256, 0, stream>>>(a2b, w2T, sup2);
  agg_lite_kernel<4, 128, false><<<(N_NODES_C / 16) * 4, 64, 0, stream>>>(
      sup2, s_meta, row_ptr, b2, nullptr, out, N_NODES_C);
}